// Round 20
// baseline (326.171 us; speedup 1.0000x reference)
//
#include <hip/hip_runtime.h>
#include <hip/hip_bf16.h>

// GLIFR forward, MI355X.
//   xbt = x transposed to (t*64+b) rows, bf16. WcatT = [W_lat ; W_iv]^T (N=H rows, K=2560).
//   chunk 0: P0 = x_0 @ W_iv                     (GEMM <64,64> 8w, 640 blocks, K=512)
//   chunk c>=1: {P0,P1} = [F[c-1] | x_c] @ Wcat  (GEMM <128,128> 16w, split-K=2, 320 blocks)
//   k_rec: syn = sum(P); ASC/volt/firing x20 -> F bf16  (512 blocks x 256 thr,
//          1 neuron/thread; chunk 0 zero-inits state in-register)
//   out(B,T,O) f32 = F @ w_out + b_out           (GEMM <128,128> 16w/1024thr, 400 blocks)
// GEMM: template<BM,BN,WGM,WGN>, 2-stage dbuf LDS, early-issue global_load_lds
// w16, XOR-chunk swizzle (0 bank conflicts), bijective XCD block swizzle,
// split-K via separate bf16 partial buffers summed by k_rec, LDS-staged
// coalesced epilogue (full-cacheline C stores).

#define B_ 64
#define T_ 200
#define I_ 512
#define H_ 2048
#define O_ 512
#define BH_ 131072
#define DELAY_ 20
#define DT_ 0.05f
#define RMEM_ 0.1f

typedef __bf16 bf16x8 __attribute__((ext_vector_type(8)));
typedef float f32x4 __attribute__((ext_vector_type(4)));

__device__ __forceinline__ unsigned short f2bf(float f) {
    unsigned int u = __builtin_bit_cast(unsigned int, f);
    u = (u + 0x7fff + ((u >> 16) & 1)) >> 16;
    return (unsigned short)u;
}
__device__ __forceinline__ float bf2f(unsigned short u) {
    return __builtin_bit_cast(float, (unsigned int)u << 16);
}

__device__ __forceinline__ void gload16(const void* g, void* l) {
    __builtin_amdgcn_global_load_lds(
        (const __attribute__((address_space(1))) unsigned int*)g,
        (__attribute__((address_space(3))) unsigned int*)l, 16, 0, 0);
}

// ---------- x (B,T,I) f32 -> xbt rows (t*64+b) x I, bf16 ----------
__global__ void k_cvt_tb(const float* __restrict__ in, unsigned short* __restrict__ out) {
    int g = blockIdx.x * 256 + threadIdx.x;        // 4-elem group
    int idx = g * 4;
    int r = idx >> 9;                              // out row (t*64+b)
    int i0 = idx & 511;
    int t = r >> 6, b = r & 63;
    float4 v = *(const float4*)(in + ((size_t)b * T_ + t) * I_ + i0);
    ushort4 o;
    o.x = f2bf(v.x); o.y = f2bf(v.y); o.z = f2bf(v.z); o.w = f2bf(v.w);
    *(ushort4*)(out + idx) = o;
}

// ---------- f32 (R x C) -> bf16 transposed rows C x (ldo), at col ooff ----------
__global__ __launch_bounds__(256) void k_tcvt(const float* __restrict__ in,
                                              unsigned short* __restrict__ out,
                                              int R, int C, int ldo, int ooff) {
    __shared__ float t[32][33];
    int bx = blockIdx.x, by = blockIdx.y;
    int tx = threadIdx.x & 31, ty = threadIdx.x >> 5;
    #pragma unroll
    for (int r = 0; r < 32; r += 8)
        t[ty + r][tx] = in[(size_t)(by * 32 + ty + r) * C + bx * 32 + tx];
    __syncthreads();
    #pragma unroll
    for (int r = 0; r < 32; r += 8)
        out[(size_t)(bx * 32 + ty + r) * ldo + ooff + by * 32 + tx] = f2bf(t[tx][ty + r]);
}

// ---------- bf16 GEMM, WGM x WGN wave grid: C = A(MxK) * Bt(NxK)^T ----------
// A split along K: cols [0,k1) from A1 (lda1), [k1,K) from A2 (lda2).
// B element (n,k) = Bt[n*ldbt + kboff + k].
// ksplit: block computes K-slice and writes bf16 partial C + split*csplit.
// cbf16==0: f32 out (+bias), cmap: row m -> (m&63)*200 + (m>>6).
template<int BM, int BN, int WGM, int WGN>
__global__ __launch_bounds__(WGM * WGN * 64) void k_gemm(
    const unsigned short* __restrict__ A1, const unsigned short* __restrict__ A2,
    const unsigned short* __restrict__ Bt, void* __restrict__ Cv,
    const float* __restrict__ bias,
    int k1, int K, int lda1, int lda2, int ldbt, int kboff, int ldc,
    int cmap, int cbf16, int ksplit, long long csplit, int gx, int gy)
{
    constexpr int NT = WGM * WGN * 64;
    constexpr int AIT = (BM * 8) / NT, BIT = (BN * 8) / NT;  // 16B gloads/thread/stage
    constexpr int ASZ = BM * 64, BSZ = BN * 64;
    constexpr int WTM = BM / WGM, WTN = BN / WGN;
    constexpr int FM = WTM / 16, FN = WTN / 16;
    constexpr int SMAIN = 2 * (ASZ + BSZ) * 2;               // bytes, staged A+B
    constexpr int SEPI = BM * BN * 4;                        // bytes, f32 C tile
    constexpr int SBYTES = SMAIN > SEPI ? SMAIN : SEPI;
    __shared__ char smem[SBYTES];
    unsigned short* As = (unsigned short*)smem;
    unsigned short* Bs = As + 2 * ASZ;

    const int nb = gx * gy * ksplit;
    const int hw = blockIdx.x;
    const int wid = (hw & 7) * (nb >> 3) + (hw >> 3);
    const int layer = gx * gy;
    const int split = wid / layer;
    const int w2 = wid % layer;
    int bm, bn;
    if (gx <= gy) { bn = w2 % gx; bm = w2 / gx; }
    else          { bm = w2 % gy; bn = w2 / gy; }

    const int klen = K / ksplit;
    const int nk = klen >> 6;
    const int kb = (split * klen) >> 6;     // base k-tile

    const int tid = threadIdx.x;
    const int lane = tid & 63, wave = tid >> 6;
    const int wr = (wave / WGN) * WTM, wc = (wave % WGN) * WTN;
    const int fr = lane & 15, kg = lane >> 4;
    const int rx = fr & 7;

    // staging: slot s = (row, cp); global chunk cg = cp ^ (row&7)
    int arow[AIT], acg[AIT], lsA[AIT];
    #pragma unroll
    for (int it = 0; it < AIT; ++it) {
        int s = tid + it * NT;
        int row = s >> 3, cp = s & 7;
        acg[it] = (cp ^ (row & 7)) * 8;
        arow[it] = bm * BM + row;
        lsA[it] = s * 8;
    }
    const unsigned short* Bp[BIT]; int lsB[BIT];
    #pragma unroll
    for (int it = 0; it < BIT; ++it) {
        int s = tid + it * NT;
        int row = s >> 3, cp = s & 7, cg = cp ^ (row & 7);
        Bp[it] = Bt + (size_t)(bn * BN + row) * ldbt + kboff + cg * 8;
        lsB[it] = s * 8;
    }

    auto stage = [&](int buf, int ktg) {
        const int kc = ktg << 6;
        #pragma unroll
        for (int it = 0; it < AIT; ++it) {
            int kcol = kc + acg[it];
            const unsigned short* p = (kcol < k1)
                ? A1 + (size_t)arow[it] * lda1 + kcol
                : A2 + (size_t)arow[it] * lda2 + (kcol - k1);
            gload16(p, &As[buf * ASZ + lsA[it]]);
        }
        #pragma unroll
        for (int it = 0; it < BIT; ++it)
            gload16(Bp[it] + kc, &Bs[buf * BSZ + lsB[it]]);
    };

    f32x4 acc[FM][FN] = {};

    stage(0, kb);
    __syncthreads();
    for (int t = 0; t < nk; ++t) {
        const int cur = t & 1;
        if (t + 1 < nk) stage(cur ^ 1, kb + t + 1);   // issue next-tile loads first
        #pragma unroll
        for (int kk = 0; kk < 2; ++kk) {
            const int ck = (kk << 2) | kg;
            bf16x8 af[FM], bfr[FN];
            #pragma unroll
            for (int i = 0; i < FM; ++i)
                af[i] = *(const bf16x8*)(&As[cur * ASZ + (wr + i * 16 + fr) * 64 + ((ck ^ rx) << 3)]);
            #pragma unroll
            for (int j = 0; j < FN; ++j)
                bfr[j] = *(const bf16x8*)(&Bs[cur * BSZ + (wc + j * 16 + fr) * 64 + ((ck ^ rx) << 3)]);
            #pragma unroll
            for (int i = 0; i < FM; ++i)
                #pragma unroll
                for (int j = 0; j < FN; ++j)
                    acc[i][j] = __builtin_amdgcn_mfma_f32_16x16x32_bf16(af[i], bfr[j], acc[i][j], 0, 0, 0);
        }
        __syncthreads();
    }

    // ---- LDS-staged epilogue: full-cacheline coalesced C stores ----
    if (cbf16) {
        unsigned short* Cs = (unsigned short*)smem;
        #pragma unroll
        for (int i = 0; i < FM; ++i)
            #pragma unroll
            for (int j = 0; j < FN; ++j)
                #pragma unroll
                for (int r = 0; r < 4; ++r)
                    Cs[(wr + i * 16 + kg * 4 + r) * BN + wc + j * 16 + fr] = f2bf(acc[i][j][r]);
        __syncthreads();
        unsigned short* Cb = (unsigned short*)Cv + (size_t)split * csplit;
        constexpr int NCH = BM * BN / 8;          // 16B chunks
        #pragma unroll
        for (int s0 = 0; s0 < NCH; s0 += NT) {
            int s = s0 + tid;
            if (NCH % NT != 0 && s >= NCH) break;
            int row = s / (BN / 8), c8 = s % (BN / 8);
            int m = bm * BM + row;
            *(uint4*)(Cb + (size_t)m * ldc + bn * BN + c8 * 8) = *(const uint4*)&Cs[row * BN + c8 * 8];
        }
    } else {
        float* Cs = (float*)smem;
        #pragma unroll
        for (int i = 0; i < FM; ++i)
            #pragma unroll
            for (int j = 0; j < FN; ++j) {
                int col = bn * BN + wc + j * 16 + fr;
                float b = bias ? bias[col] : 0.f;
                #pragma unroll
                for (int r = 0; r < 4; ++r)
                    Cs[(wr + i * 16 + kg * 4 + r) * BN + wc + j * 16 + fr] = acc[i][j][r] + b;
            }
        __syncthreads();
        float* Cf = (float*)Cv;
        constexpr int NCH = BM * BN / 4;          // 16B chunks
        #pragma unroll
        for (int s0 = 0; s0 < NCH; s0 += NT) {
            int s = s0 + tid;
            if (NCH % NT != 0 && s >= NCH) break;
            int row = s / (BN / 4), c4 = s % (BN / 4);
            int m = bm * BM + row;
            int cr = cmap ? ((m & 63) * 200 + (m >> 6)) : m;
            *(float4*)(Cf + (size_t)cr * ldc + bn * BN + c4 * 4) = *(const float4*)&Cs[row * BN + c4 * 4];
        }
    }
}

// ---------- per-(b,h) recurrence, 1 neuron/thread, one chunk ----------
// syn = sum_{s<NP} P[s]; 1-step register prefetch; 512 blocks x 256 threads.
template<int NP>
__global__ __launch_bounds__(256) void k_rec(
    const unsigned short* __restrict__ P, unsigned short* __restrict__ F,
    float* __restrict__ volt, float* __restrict__ fire, float* __restrict__ asc,
    const float* __restrict__ thresh, const float* __restrict__ km,
    const float* __restrict__ asc_amp, const float* __restrict__ asc_r,
    const float* __restrict__ asc_k, int t0)
{
    const size_t PSPL = (size_t)DELAY_ * BH_;
    int idx = blockIdx.x * 256 + threadIdx.x;
    int h = idx & (H_ - 1);
    float v, f, a0, a1;
    if (t0 == 0) { v = 0.f; f = 0.f; a0 = 0.f; a1 = 0.f; }
    else { v = volt[idx]; f = fire[idx]; a0 = asc[idx]; a1 = asc[BH_ + idx]; }
    float th = thresh[h], dtk = DT_ * km[h];
    float amp0 = asc_amp[h], amp1 = asc_amp[H_ + h];
    float r0 = asc_r[h], r1 = asc_r[H_ + h];
    float d0 = expf(-DT_ * asc_k[h]), d1 = expf(-DT_ * asc_k[H_ + h]);
    unsigned short pa[NP], pb[NP];
    #pragma unroll
    for (int s = 0; s < NP; ++s) pa[s] = P[s * PSPL + idx];
    for (int t = 0; t < DELAY_; ++t) {
        if (t + 1 < DELAY_) {
            #pragma unroll
            for (int s = 0; s < NP; ++s)
                pb[s] = P[s * PSPL + (size_t)(t + 1) * BH_ + idx];
        }
        float syn = 0.f;
        #pragma unroll
        for (int s = 0; s < NP; ++s) syn += bf2f(pa[s]);
        float na0 = a0 * d0 + f * (r0 * a0 + amp0);
        float na1 = a1 * d1 + f * (r1 * a1 + amp1);
        a0 = na0; a1 = na1;
        float tot = syn + a0 + a1;
        v = v * (1.f - f);
        v = v + dtk * (RMEM_ * tot - v);
        f = 1.f / (1.f + __expf(-(v - th)));
        F[(size_t)(t0 + t) * BH_ + idx] = f2bf(f);
        #pragma unroll
        for (int s = 0; s < NP; ++s) pa[s] = pb[s];
    }
    volt[idx] = v; fire[idx] = f;
    asc[idx] = a0; asc[BH_ + idx] = a1;
}

extern "C" void kernel_launch(void* const* d_in, const int* in_sizes, int n_in,
                              void* d_out, int out_size, void* d_ws, size_t ws_size,
                              hipStream_t stream) {
    const float* x       = (const float*)d_in[0];
    const float* w_iv    = (const float*)d_in[1];
    const float* w_lat   = (const float*)d_in[2];
    const float* thresh  = (const float*)d_in[3];
    const float* km      = (const float*)d_in[4];
    const float* asc_amp = (const float*)d_in[5];
    const float* asc_r   = (const float*)d_in[6];
    const float* asc_k   = (const float*)d_in[7];
    const float* w_out   = (const float*)d_in[8];
    const float* b_out   = (const float*)d_in[9];
    float* out = (float*)d_out;

    char* ws = (char*)d_ws;
    unsigned short* P     = (unsigned short*)ws;                          // 10,485,760 (2 partials)
    unsigned short* Fb    = (unsigned short*)(ws + 10485760);             // 52,428,800 (T,B,H) bf16
    unsigned short* xbt   = (unsigned short*)(ws + 62914560);             // 13,107,200 (T*B x I) bf16
    unsigned short* WcatT = (unsigned short*)(ws + 76021760);             // 10,485,760 (H x 2560)
    unsigned short* WoutT = (unsigned short*)(ws + 86507520);             //  2,097,152 (O x H)
    float*          volt  = (float*)(ws + 88604672);
    float*          fire  = (float*)(ws + 89128960);
    float*          asc   = (float*)(ws + 89653248);                      // 2*BH f32

    k_cvt_tb<<<(T_ * B_ * I_ / 4) / 256, 256, 0, stream>>>(x, xbt);
    k_tcvt<<<dim3(H_ / 32, H_ / 32), 256, 0, stream>>>(w_lat, WcatT, H_, H_, 2560, 0);
    k_tcvt<<<dim3(H_ / 32, I_ / 32), 256, 0, stream>>>(w_iv, WcatT, I_, H_, 2560, 2048);
    k_tcvt<<<dim3(O_ / 32, H_ / 32), 256, 0, stream>>>(w_out, WoutT, H_, O_, 2048, 0);

    // chunk 0: P0 = x_0 @ W_iv  (K=512 via x-part of Wcat) : <64,64> 8w, 640 blocks
    k_gemm<64, 64, 4, 2><<<(DELAY_ * B_ / 64) * (H_ / 64), 512, 0, stream>>>(
        nullptr, xbt, WcatT, P, nullptr,
        0, I_, 0, I_, 2560, 2048, H_, 0, 1, 1, 0, H_ / 64, DELAY_ * B_ / 64);
    k_rec<1><<<BH_ / 256, 256, 0, stream>>>(P, Fb, volt, fire, asc,
                                            thresh, km, asc_amp, asc_r, asc_k, 0);

    for (int c = 1; c < T_ / DELAY_; ++c) {
        // {P0,P1} = [F[c-1] | x_c] @ Wcat : <128,128> 16w, split-K=2, 320 blocks
        k_gemm<128, 128, 4, 4><<<(DELAY_ * B_ / 128) * (H_ / 128) * 2, 1024, 0, stream>>>(
            Fb + (size_t)(c - 1) * DELAY_ * BH_, xbt + (size_t)c * DELAY_ * B_ * I_,
            WcatT, P, nullptr,
            H_, H_ + I_, H_, I_, 2560, 0, H_, 0, 1, 2, (long long)DELAY_ * BH_,
            H_ / 128, DELAY_ * B_ / 128);
        k_rec<2><<<BH_ / 256, 256, 0, stream>>>(P, Fb, volt, fire, asc,
                                                thresh, km, asc_amp, asc_r, asc_k, c * DELAY_);
    }

    // out = F @ w_out + b_out : <128,128> 16 waves / 1024 thr, 400 blocks
    k_gemm<128, 128, 4, 4><<<(B_ * T_ / 128) * (O_ / 128), 1024, 0, stream>>>(
        nullptr, Fb, WoutT, out, b_out,
        0, H_, 0, H_, H_, 0, O_, 1, 0, 1, 0, O_ / 128, B_ * T_ / 128);
}

// Round 21
// 319.808 us; speedup vs baseline: 1.0199x; 1.0199x over previous
//
#include <hip/hip_runtime.h>
#include <hip/hip_bf16.h>

// GLIFR forward, MI355X.
//   xbt = x transposed to (t*64+b) rows, bf16. WcatT = [W_lat ; W_iv]^T (N=H rows, K=2560).
//   chunk 0: P0 = x_0 @ W_iv                     (GEMM <64,64> 8w, 640 blocks, K=512)
//   chunk c>=1: {P0,P1} = [F[c-1] | x_c] @ Wcat  (GEMM <128,64> 8w, split-K=2, 640 blocks)
//   k_rec: syn = sum(P); ASC/volt/firing x20 -> F bf16  (512 blocks x 256 thr,
//          1 neuron/thread; chunk 0 zero-inits state in-register)
//   out(B,T,O) f32 = F @ w_out + b_out           (GEMM <128,128> 16w/1024thr, 400 blocks)
// GEMM: template<BM,BN,WGM,WGN>, 2-stage dbuf LDS, early-issue global_load_lds
// w16, XOR-chunk swizzle (0 bank conflicts), bijective XCD block swizzle,
// split-K via separate bf16 partial buffers summed by k_rec, LDS-staged
// coalesced epilogue (full-cacheline C stores). All three weight transposes
// merged into one block-range dispatch.

#define B_ 64
#define T_ 200
#define I_ 512
#define H_ 2048
#define O_ 512
#define BH_ 131072
#define DELAY_ 20
#define DT_ 0.05f
#define RMEM_ 0.1f

typedef __bf16 bf16x8 __attribute__((ext_vector_type(8)));
typedef float f32x4 __attribute__((ext_vector_type(4)));

__device__ __forceinline__ unsigned short f2bf(float f) {
    unsigned int u = __builtin_bit_cast(unsigned int, f);
    u = (u + 0x7fff + ((u >> 16) & 1)) >> 16;
    return (unsigned short)u;
}
__device__ __forceinline__ float bf2f(unsigned short u) {
    return __builtin_bit_cast(float, (unsigned int)u << 16);
}

__device__ __forceinline__ void gload16(const void* g, void* l) {
    __builtin_amdgcn_global_load_lds(
        (const __attribute__((address_space(1))) unsigned int*)g,
        (__attribute__((address_space(3))) unsigned int*)l, 16, 0, 0);
}

// ---------- x (B,T,I) f32 -> xbt rows (t*64+b) x I, bf16 ----------
__global__ void k_cvt_tb(const float* __restrict__ in, unsigned short* __restrict__ out) {
    int g = blockIdx.x * 256 + threadIdx.x;        // 4-elem group
    int idx = g * 4;
    int r = idx >> 9;                              // out row (t*64+b)
    int i0 = idx & 511;
    int t = r >> 6, b = r & 63;
    float4 v = *(const float4*)(in + ((size_t)b * T_ + t) * I_ + i0);
    ushort4 o;
    o.x = f2bf(v.x); o.y = f2bf(v.y); o.z = f2bf(v.z); o.w = f2bf(v.w);
    *(ushort4*)(out + idx) = o;
}

// ---------- merged weight transpose: 3 jobs, one dispatch ----------
// job j: in (R x C) f32 -> out rows C x ldo bf16 at col ooff. 32x32 tiles.
struct TJob { const float* in; unsigned short* out; int R, C, ldo, ooff, gx; };
__global__ __launch_bounds__(256) void k_tcvt3(TJob j0, TJob j1, TJob j2, int n0, int n1) {
    __shared__ float t[32][33];
    int hw = blockIdx.x;
    TJob J; int lt;
    if (hw < n0)            { J = j0; lt = hw; }
    else if (hw < n0 + n1)  { J = j1; lt = hw - n0; }
    else                    { J = j2; lt = hw - n0 - n1; }
    int bx = lt % J.gx, by = lt / J.gx;
    int tx = threadIdx.x & 31, ty = threadIdx.x >> 5;
    #pragma unroll
    for (int r = 0; r < 32; r += 8)
        t[ty + r][tx] = J.in[(size_t)(by * 32 + ty + r) * J.C + bx * 32 + tx];
    __syncthreads();
    #pragma unroll
    for (int r = 0; r < 32; r += 8)
        J.out[(size_t)(bx * 32 + ty + r) * J.ldo + J.ooff + by * 32 + tx] = f2bf(t[tx][ty + r]);
}

// ---------- bf16 GEMM, WGM x WGN wave grid: C = A(MxK) * Bt(NxK)^T ----------
// A split along K: cols [0,k1) from A1 (lda1), [k1,K) from A2 (lda2).
// B element (n,k) = Bt[n*ldbt + kboff + k].
// ksplit: block computes K-slice and writes bf16 partial C + split*csplit.
// cbf16==0: f32 out (+bias), cmap: row m -> (m&63)*200 + (m>>6).
template<int BM, int BN, int WGM, int WGN>
__global__ __launch_bounds__(WGM * WGN * 64) void k_gemm(
    const unsigned short* __restrict__ A1, const unsigned short* __restrict__ A2,
    const unsigned short* __restrict__ Bt, void* __restrict__ Cv,
    const float* __restrict__ bias,
    int k1, int K, int lda1, int lda2, int ldbt, int kboff, int ldc,
    int cmap, int cbf16, int ksplit, long long csplit, int gx, int gy)
{
    constexpr int NT = WGM * WGN * 64;
    constexpr int AIT = (BM * 8) / NT, BIT = (BN * 8) / NT;  // 16B gloads/thread/stage
    constexpr int ASZ = BM * 64, BSZ = BN * 64;
    constexpr int WTM = BM / WGM, WTN = BN / WGN;
    constexpr int FM = WTM / 16, FN = WTN / 16;
    constexpr int SMAIN = 2 * (ASZ + BSZ) * 2;               // bytes, staged A+B
    constexpr int SEPI = BM * BN * 4;                        // bytes, f32 C tile
    constexpr int SBYTES = SMAIN > SEPI ? SMAIN : SEPI;
    __shared__ char smem[SBYTES];
    unsigned short* As = (unsigned short*)smem;
    unsigned short* Bs = As + 2 * ASZ;

    const int nb = gx * gy * ksplit;
    const int hw = blockIdx.x;
    const int wid = (hw & 7) * (nb >> 3) + (hw >> 3);
    const int layer = gx * gy;
    const int split = wid / layer;
    const int w2 = wid % layer;
    int bm, bn;
    if (gx <= gy) { bn = w2 % gx; bm = w2 / gx; }
    else          { bm = w2 % gy; bn = w2 / gy; }

    const int klen = K / ksplit;
    const int nk = klen >> 6;
    const int kb = (split * klen) >> 6;     // base k-tile

    const int tid = threadIdx.x;
    const int lane = tid & 63, wave = tid >> 6;
    const int wr = (wave / WGN) * WTM, wc = (wave % WGN) * WTN;
    const int fr = lane & 15, kg = lane >> 4;
    const int rx = fr & 7;

    // staging: slot s = (row, cp); global chunk cg = cp ^ (row&7)
    int arow[AIT], acg[AIT], lsA[AIT];
    #pragma unroll
    for (int it = 0; it < AIT; ++it) {
        int s = tid + it * NT;
        int row = s >> 3, cp = s & 7;
        acg[it] = (cp ^ (row & 7)) * 8;
        arow[it] = bm * BM + row;
        lsA[it] = s * 8;
    }
    const unsigned short* Bp[BIT]; int lsB[BIT];
    #pragma unroll
    for (int it = 0; it < BIT; ++it) {
        int s = tid + it * NT;
        int row = s >> 3, cp = s & 7, cg = cp ^ (row & 7);
        Bp[it] = Bt + (size_t)(bn * BN + row) * ldbt + kboff + cg * 8;
        lsB[it] = s * 8;
    }

    auto stage = [&](int buf, int ktg) {
        const int kc = ktg << 6;
        #pragma unroll
        for (int it = 0; it < AIT; ++it) {
            int kcol = kc + acg[it];
            const unsigned short* p = (kcol < k1)
                ? A1 + (size_t)arow[it] * lda1 + kcol
                : A2 + (size_t)arow[it] * lda2 + (kcol - k1);
            gload16(p, &As[buf * ASZ + lsA[it]]);
        }
        #pragma unroll
        for (int it = 0; it < BIT; ++it)
            gload16(Bp[it] + kc, &Bs[buf * BSZ + lsB[it]]);
    };

    f32x4 acc[FM][FN] = {};

    stage(0, kb);
    __syncthreads();
    for (int t = 0; t < nk; ++t) {
        const int cur = t & 1;
        if (t + 1 < nk) stage(cur ^ 1, kb + t + 1);   // issue next-tile loads first
        #pragma unroll
        for (int kk = 0; kk < 2; ++kk) {
            const int ck = (kk << 2) | kg;
            bf16x8 af[FM], bfr[FN];
            #pragma unroll
            for (int i = 0; i < FM; ++i)
                af[i] = *(const bf16x8*)(&As[cur * ASZ + (wr + i * 16 + fr) * 64 + ((ck ^ rx) << 3)]);
            #pragma unroll
            for (int j = 0; j < FN; ++j)
                bfr[j] = *(const bf16x8*)(&Bs[cur * BSZ + (wc + j * 16 + fr) * 64 + ((ck ^ rx) << 3)]);
            #pragma unroll
            for (int i = 0; i < FM; ++i)
                #pragma unroll
                for (int j = 0; j < FN; ++j)
                    acc[i][j] = __builtin_amdgcn_mfma_f32_16x16x32_bf16(af[i], bfr[j], acc[i][j], 0, 0, 0);
        }
        __syncthreads();
    }

    // ---- LDS-staged epilogue: full-cacheline coalesced C stores ----
    if (cbf16) {
        unsigned short* Cs = (unsigned short*)smem;
        #pragma unroll
        for (int i = 0; i < FM; ++i)
            #pragma unroll
            for (int j = 0; j < FN; ++j)
                #pragma unroll
                for (int r = 0; r < 4; ++r)
                    Cs[(wr + i * 16 + kg * 4 + r) * BN + wc + j * 16 + fr] = f2bf(acc[i][j][r]);
        __syncthreads();
        unsigned short* Cb = (unsigned short*)Cv + (size_t)split * csplit;
        constexpr int NCH = BM * BN / 8;          // 16B chunks
        #pragma unroll
        for (int s0 = 0; s0 < NCH; s0 += NT) {
            int s = s0 + tid;
            if (NCH % NT != 0 && s >= NCH) break;
            int row = s / (BN / 8), c8 = s % (BN / 8);
            int m = bm * BM + row;
            *(uint4*)(Cb + (size_t)m * ldc + bn * BN + c8 * 8) = *(const uint4*)&Cs[row * BN + c8 * 8];
        }
    } else {
        float* Cs = (float*)smem;
        #pragma unroll
        for (int i = 0; i < FM; ++i)
            #pragma unroll
            for (int j = 0; j < FN; ++j) {
                int col = bn * BN + wc + j * 16 + fr;
                float b = bias ? bias[col] : 0.f;
                #pragma unroll
                for (int r = 0; r < 4; ++r)
                    Cs[(wr + i * 16 + kg * 4 + r) * BN + wc + j * 16 + fr] = acc[i][j][r] + b;
            }
        __syncthreads();
        float* Cf = (float*)Cv;
        constexpr int NCH = BM * BN / 4;          // 16B chunks
        #pragma unroll
        for (int s0 = 0; s0 < NCH; s0 += NT) {
            int s = s0 + tid;
            if (NCH % NT != 0 && s >= NCH) break;
            int row = s / (BN / 4), c4 = s % (BN / 4);
            int m = bm * BM + row;
            int cr = cmap ? ((m & 63) * 200 + (m >> 6)) : m;
            *(float4*)(Cf + (size_t)cr * ldc + bn * BN + c4 * 4) = *(const float4*)&Cs[row * BN + c4 * 4];
        }
    }
}

// ---------- per-(b,h) recurrence, 1 neuron/thread, one chunk ----------
// syn = sum_{s<NP} P[s]; 1-step register prefetch; 512 blocks x 256 threads.
template<int NP>
__global__ __launch_bounds__(256) void k_rec(
    const unsigned short* __restrict__ P, unsigned short* __restrict__ F,
    float* __restrict__ volt, float* __restrict__ fire, float* __restrict__ asc,
    const float* __restrict__ thresh, const float* __restrict__ km,
    const float* __restrict__ asc_amp, const float* __restrict__ asc_r,
    const float* __restrict__ asc_k, int t0)
{
    const size_t PSPL = (size_t)DELAY_ * BH_;
    int idx = blockIdx.x * 256 + threadIdx.x;
    int h = idx & (H_ - 1);
    float v, f, a0, a1;
    if (t0 == 0) { v = 0.f; f = 0.f; a0 = 0.f; a1 = 0.f; }
    else { v = volt[idx]; f = fire[idx]; a0 = asc[idx]; a1 = asc[BH_ + idx]; }
    float th = thresh[h], dtk = DT_ * km[h];
    float amp0 = asc_amp[h], amp1 = asc_amp[H_ + h];
    float r0 = asc_r[h], r1 = asc_r[H_ + h];
    float d0 = expf(-DT_ * asc_k[h]), d1 = expf(-DT_ * asc_k[H_ + h]);
    unsigned short pa[NP], pb[NP];
    #pragma unroll
    for (int s = 0; s < NP; ++s) pa[s] = P[s * PSPL + idx];
    for (int t = 0; t < DELAY_; ++t) {
        if (t + 1 < DELAY_) {
            #pragma unroll
            for (int s = 0; s < NP; ++s)
                pb[s] = P[s * PSPL + (size_t)(t + 1) * BH_ + idx];
        }
        float syn = 0.f;
        #pragma unroll
        for (int s = 0; s < NP; ++s) syn += bf2f(pa[s]);
        float na0 = a0 * d0 + f * (r0 * a0 + amp0);
        float na1 = a1 * d1 + f * (r1 * a1 + amp1);
        a0 = na0; a1 = na1;
        float tot = syn + a0 + a1;
        v = v * (1.f - f);
        v = v + dtk * (RMEM_ * tot - v);
        f = 1.f / (1.f + __expf(-(v - th)));
        F[(size_t)(t0 + t) * BH_ + idx] = f2bf(f);
        #pragma unroll
        for (int s = 0; s < NP; ++s) pa[s] = pb[s];
    }
    volt[idx] = v; fire[idx] = f;
    asc[idx] = a0; asc[BH_ + idx] = a1;
}

extern "C" void kernel_launch(void* const* d_in, const int* in_sizes, int n_in,
                              void* d_out, int out_size, void* d_ws, size_t ws_size,
                              hipStream_t stream) {
    const float* x       = (const float*)d_in[0];
    const float* w_iv    = (const float*)d_in[1];
    const float* w_lat   = (const float*)d_in[2];
    const float* thresh  = (const float*)d_in[3];
    const float* km      = (const float*)d_in[4];
    const float* asc_amp = (const float*)d_in[5];
    const float* asc_r   = (const float*)d_in[6];
    const float* asc_k   = (const float*)d_in[7];
    const float* w_out   = (const float*)d_in[8];
    const float* b_out   = (const float*)d_in[9];
    float* out = (float*)d_out;

    char* ws = (char*)d_ws;
    unsigned short* P     = (unsigned short*)ws;                          // 10,485,760 (2 partials)
    unsigned short* Fb    = (unsigned short*)(ws + 10485760);             // 52,428,800 (T,B,H) bf16
    unsigned short* xbt   = (unsigned short*)(ws + 62914560);             // 13,107,200 (T*B x I) bf16
    unsigned short* WcatT = (unsigned short*)(ws + 76021760);             // 10,485,760 (H x 2560)
    unsigned short* WoutT = (unsigned short*)(ws + 86507520);             //  2,097,152 (O x H)
    float*          volt  = (float*)(ws + 88604672);
    float*          fire  = (float*)(ws + 89128960);
    float*          asc   = (float*)(ws + 89653248);                      // 2*BH f32

    k_cvt_tb<<<(T_ * B_ * I_ / 4) / 256, 256, 0, stream>>>(x, xbt);
    {
        TJob j0{w_lat, WcatT, H_, H_, 2560, 0,    H_ / 32};   // 64x64 = 4096 blocks
        TJob j1{w_iv,  WcatT, I_, H_, 2560, 2048, H_ / 32};   // 64x16 = 1024
        TJob j2{w_out, WoutT, H_, O_, 2048, 0,    O_ / 32};   // 16x64 = 1024
        k_tcvt3<<<6144, 256, 0, stream>>>(j0, j1, j2, 4096, 1024);
    }

    // chunk 0: P0 = x_0 @ W_iv  (K=512 via x-part of Wcat) : <64,64> 8w, 640 blocks
    k_gemm<64, 64, 4, 2><<<(DELAY_ * B_ / 64) * (H_ / 64), 512, 0, stream>>>(
        nullptr, xbt, WcatT, P, nullptr,
        0, I_, 0, I_, 2560, 2048, H_, 0, 1, 1, 0, H_ / 64, DELAY_ * B_ / 64);
    k_rec<1><<<BH_ / 256, 256, 0, stream>>>(P, Fb, volt, fire, asc,
                                            thresh, km, asc_amp, asc_r, asc_k, 0);

    for (int c = 1; c < T_ / DELAY_; ++c) {
        // {P0,P1} = [F[c-1] | x_c] @ Wcat : <128,64> 8w, split-K=2, 640 blocks
        k_gemm<128, 64, 4, 2><<<(DELAY_ * B_ / 128) * (H_ / 64) * 2, 512, 0, stream>>>(
            Fb + (size_t)(c - 1) * DELAY_ * BH_, xbt + (size_t)c * DELAY_ * B_ * I_,
            WcatT, P, nullptr,
            H_, H_ + I_, H_, I_, 2560, 0, H_, 0, 1, 2, (long long)DELAY_ * BH_,
            H_ / 64, DELAY_ * B_ / 128);
        k_rec<2><<<BH_ / 256, 256, 0, stream>>>(P, Fb, volt, fire, asc,
                                                thresh, km, asc_amp, asc_r, asc_k, c * DELAY_);
    }

    // out = F @ w_out + b_out : <128,128> 16 waves / 1024 thr, 400 blocks
    k_gemm<128, 128, 4, 4><<<(B_ * T_ / 128) * (O_ / 128), 1024, 0, stream>>>(
        nullptr, Fb, WoutT, out, b_out,
        0, H_, 0, H_, H_, 0, O_, 1, 0, 1, 0, O_ / 128, B_ * T_ / 128);
}

// Round 22
// 317.156 us; speedup vs baseline: 1.0284x; 1.0084x over previous
//
#include <hip/hip_runtime.h>
#include <hip/hip_bf16.h>

// GLIFR forward, MI355X.
//   preamble (ONE dispatch): 3 weight transposes + x->(t*64+b)-row bf16 convert
//   chunk 0: P0 = x_0 @ W_iv                     (GEMM <64,64> 8w, 640 blocks, K=512)
//   chunk c>=1: {P0,P1} = [F[c-1] | x_c] @ Wcat  (GEMM <128,64> 8w, split-K=2, 640 blocks)
//   k_rec: syn = sum(P); ASC/volt/firing x20 -> F bf16  (512 blocks x 256 thr,
//          1 neuron/thread; chunk 0 zero-inits state in-register)
//   out(B,T,O) f32 = F @ w_out + b_out           (GEMM <128,128> 16w/1024thr, 400 blocks)
// GEMM: template<BM,BN,WGM,WGN>, 2-stage dbuf LDS, early-issue global_load_lds
// w16, XOR-chunk swizzle (0 bank conflicts), bijective XCD block swizzle,
// split-K via separate bf16 partial buffers summed by k_rec, LDS-staged
// coalesced epilogue (full-cacheline C stores).

#define B_ 64
#define T_ 200
#define I_ 512
#define H_ 2048
#define O_ 512
#define BH_ 131072
#define DELAY_ 20
#define DT_ 0.05f
#define RMEM_ 0.1f

typedef __bf16 bf16x8 __attribute__((ext_vector_type(8)));
typedef float f32x4 __attribute__((ext_vector_type(4)));

__device__ __forceinline__ unsigned short f2bf(float f) {
    unsigned int u = __builtin_bit_cast(unsigned int, f);
    u = (u + 0x7fff + ((u >> 16) & 1)) >> 16;
    return (unsigned short)u;
}
__device__ __forceinline__ float bf2f(unsigned short u) {
    return __builtin_bit_cast(float, (unsigned int)u << 16);
}

__device__ __forceinline__ void gload16(const void* g, void* l) {
    __builtin_amdgcn_global_load_lds(
        (const __attribute__((address_space(1))) unsigned int*)g,
        (__attribute__((address_space(3))) unsigned int*)l, 16, 0, 0);
}

// ---------- merged preamble: 3 weight transposes + x convert, one dispatch ----
// transpose job j: in (R x C) f32 -> out rows C x ldo bf16 at col ooff (32x32).
// blocks >= n0+n1+n2: x (B,T,I) f32 -> xbt rows (t*64+b) x I bf16, 1024 elems/blk.
struct TJob { const float* in; unsigned short* out; int R, C, ldo, ooff, gx; };
__global__ __launch_bounds__(256) void k_pre(TJob j0, TJob j1, TJob j2,
                                             int n0, int n1, int n2,
                                             const float* __restrict__ x,
                                             unsigned short* __restrict__ xbt) {
    __shared__ float t[32][33];
    int hw = blockIdx.x;
    int nT = n0 + n1 + n2;
    if (hw >= nT) {
        int g = (hw - nT) * 256 + threadIdx.x;     // 4-elem group
        int idx = g * 4;
        int r = idx >> 9;                          // out row (t*64+b)
        int i0 = idx & 511;
        int tt = r >> 6, b = r & 63;
        float4 v = *(const float4*)(x + ((size_t)b * T_ + tt) * I_ + i0);
        ushort4 o;
        o.x = f2bf(v.x); o.y = f2bf(v.y); o.z = f2bf(v.z); o.w = f2bf(v.w);
        *(ushort4*)(xbt + idx) = o;
        return;
    }
    TJob J; int lt;
    if (hw < n0)            { J = j0; lt = hw; }
    else if (hw < n0 + n1)  { J = j1; lt = hw - n0; }
    else                    { J = j2; lt = hw - n0 - n1; }
    int bx = lt % J.gx, by = lt / J.gx;
    int tx = threadIdx.x & 31, ty = threadIdx.x >> 5;
    #pragma unroll
    for (int r = 0; r < 32; r += 8)
        t[ty + r][tx] = J.in[(size_t)(by * 32 + ty + r) * J.C + bx * 32 + tx];
    __syncthreads();
    #pragma unroll
    for (int r = 0; r < 32; r += 8)
        J.out[(size_t)(bx * 32 + ty + r) * J.ldo + J.ooff + by * 32 + tx] = f2bf(t[tx][ty + r]);
}

// ---------- bf16 GEMM, WGM x WGN wave grid: C = A(MxK) * Bt(NxK)^T ----------
// A split along K: cols [0,k1) from A1 (lda1), [k1,K) from A2 (lda2).
// B element (n,k) = Bt[n*ldbt + kboff + k].
// ksplit: block computes K-slice and writes bf16 partial C + split*csplit.
// cbf16==0: f32 out (+bias), cmap: row m -> (m&63)*200 + (m>>6).
template<int BM, int BN, int WGM, int WGN>
__global__ __launch_bounds__(WGM * WGN * 64) void k_gemm(
    const unsigned short* __restrict__ A1, const unsigned short* __restrict__ A2,
    const unsigned short* __restrict__ Bt, void* __restrict__ Cv,
    const float* __restrict__ bias,
    int k1, int K, int lda1, int lda2, int ldbt, int kboff, int ldc,
    int cmap, int cbf16, int ksplit, long long csplit, int gx, int gy)
{
    constexpr int NT = WGM * WGN * 64;
    constexpr int AIT = (BM * 8) / NT, BIT = (BN * 8) / NT;  // 16B gloads/thread/stage
    constexpr int ASZ = BM * 64, BSZ = BN * 64;
    constexpr int WTM = BM / WGM, WTN = BN / WGN;
    constexpr int FM = WTM / 16, FN = WTN / 16;
    constexpr int SMAIN = 2 * (ASZ + BSZ) * 2;               // bytes, staged A+B
    constexpr int SEPI = BM * BN * 4;                        // bytes, f32 C tile
    constexpr int SBYTES = SMAIN > SEPI ? SMAIN : SEPI;
    __shared__ char smem[SBYTES];
    unsigned short* As = (unsigned short*)smem;
    unsigned short* Bs = As + 2 * ASZ;

    const int nb = gx * gy * ksplit;
    const int hw = blockIdx.x;
    const int wid = (hw & 7) * (nb >> 3) + (hw >> 3);
    const int layer = gx * gy;
    const int split = wid / layer;
    const int w2 = wid % layer;
    int bm, bn;
    if (gx <= gy) { bn = w2 % gx; bm = w2 / gx; }
    else          { bm = w2 % gy; bn = w2 / gy; }

    const int klen = K / ksplit;
    const int nk = klen >> 6;
    const int kb = (split * klen) >> 6;     // base k-tile

    const int tid = threadIdx.x;
    const int lane = tid & 63, wave = tid >> 6;
    const int wr = (wave / WGN) * WTM, wc = (wave % WGN) * WTN;
    const int fr = lane & 15, kg = lane >> 4;
    const int rx = fr & 7;

    // staging: slot s = (row, cp); global chunk cg = cp ^ (row&7)
    int arow[AIT], acg[AIT], lsA[AIT];
    #pragma unroll
    for (int it = 0; it < AIT; ++it) {
        int s = tid + it * NT;
        int row = s >> 3, cp = s & 7;
        acg[it] = (cp ^ (row & 7)) * 8;
        arow[it] = bm * BM + row;
        lsA[it] = s * 8;
    }
    const unsigned short* Bp[BIT]; int lsB[BIT];
    #pragma unroll
    for (int it = 0; it < BIT; ++it) {
        int s = tid + it * NT;
        int row = s >> 3, cp = s & 7, cg = cp ^ (row & 7);
        Bp[it] = Bt + (size_t)(bn * BN + row) * ldbt + kboff + cg * 8;
        lsB[it] = s * 8;
    }

    auto stage = [&](int buf, int ktg) {
        const int kc = ktg << 6;
        #pragma unroll
        for (int it = 0; it < AIT; ++it) {
            int kcol = kc + acg[it];
            const unsigned short* p = (kcol < k1)
                ? A1 + (size_t)arow[it] * lda1 + kcol
                : A2 + (size_t)arow[it] * lda2 + (kcol - k1);
            gload16(p, &As[buf * ASZ + lsA[it]]);
        }
        #pragma unroll
        for (int it = 0; it < BIT; ++it)
            gload16(Bp[it] + kc, &Bs[buf * BSZ + lsB[it]]);
    };

    f32x4 acc[FM][FN] = {};

    stage(0, kb);
    __syncthreads();
    for (int t = 0; t < nk; ++t) {
        const int cur = t & 1;
        if (t + 1 < nk) stage(cur ^ 1, kb + t + 1);   // issue next-tile loads first
        #pragma unroll
        for (int kk = 0; kk < 2; ++kk) {
            const int ck = (kk << 2) | kg;
            bf16x8 af[FM], bfr[FN];
            #pragma unroll
            for (int i = 0; i < FM; ++i)
                af[i] = *(const bf16x8*)(&As[cur * ASZ + (wr + i * 16 + fr) * 64 + ((ck ^ rx) << 3)]);
            #pragma unroll
            for (int j = 0; j < FN; ++j)
                bfr[j] = *(const bf16x8*)(&Bs[cur * BSZ + (wc + j * 16 + fr) * 64 + ((ck ^ rx) << 3)]);
            #pragma unroll
            for (int i = 0; i < FM; ++i)
                #pragma unroll
                for (int j = 0; j < FN; ++j)
                    acc[i][j] = __builtin_amdgcn_mfma_f32_16x16x32_bf16(af[i], bfr[j], acc[i][j], 0, 0, 0);
        }
        __syncthreads();
    }

    // ---- LDS-staged epilogue: full-cacheline coalesced C stores ----
    if (cbf16) {
        unsigned short* Cs = (unsigned short*)smem;
        #pragma unroll
        for (int i = 0; i < FM; ++i)
            #pragma unroll
            for (int j = 0; j < FN; ++j)
                #pragma unroll
                for (int r = 0; r < 4; ++r)
                    Cs[(wr + i * 16 + kg * 4 + r) * BN + wc + j * 16 + fr] = f2bf(acc[i][j][r]);
        __syncthreads();
        unsigned short* Cb = (unsigned short*)Cv + (size_t)split * csplit;
        constexpr int NCH = BM * BN / 8;          // 16B chunks
        #pragma unroll
        for (int s0 = 0; s0 < NCH; s0 += NT) {
            int s = s0 + tid;
            if (NCH % NT != 0 && s >= NCH) break;
            int row = s / (BN / 8), c8 = s % (BN / 8);
            int m = bm * BM + row;
            *(uint4*)(Cb + (size_t)m * ldc + bn * BN + c8 * 8) = *(const uint4*)&Cs[row * BN + c8 * 8];
        }
    } else {
        float* Cs = (float*)smem;
        #pragma unroll
        for (int i = 0; i < FM; ++i)
            #pragma unroll
            for (int j = 0; j < FN; ++j) {
                int col = bn * BN + wc + j * 16 + fr;
                float b = bias ? bias[col] : 0.f;
                #pragma unroll
                for (int r = 0; r < 4; ++r)
                    Cs[(wr + i * 16 + kg * 4 + r) * BN + wc + j * 16 + fr] = acc[i][j][r] + b;
            }
        __syncthreads();
        float* Cf = (float*)Cv;
        constexpr int NCH = BM * BN / 4;          // 16B chunks
        #pragma unroll
        for (int s0 = 0; s0 < NCH; s0 += NT) {
            int s = s0 + tid;
            if (NCH % NT != 0 && s >= NCH) break;
            int row = s / (BN / 4), c4 = s % (BN / 4);
            int m = bm * BM + row;
            int cr = cmap ? ((m & 63) * 200 + (m >> 6)) : m;
            *(float4*)(Cf + (size_t)cr * ldc + bn * BN + c4 * 4) = *(const float4*)&Cs[row * BN + c4 * 4];
        }
    }
}

// ---------- per-(b,h) recurrence, 1 neuron/thread, one chunk ----------
// syn = sum_{s<NP} P[s]; 1-step register prefetch; 512 blocks x 256 threads.
template<int NP>
__global__ __launch_bounds__(256) void k_rec(
    const unsigned short* __restrict__ P, unsigned short* __restrict__ F,
    float* __restrict__ volt, float* __restrict__ fire, float* __restrict__ asc,
    const float* __restrict__ thresh, const float* __restrict__ km,
    const float* __restrict__ asc_amp, const float* __restrict__ asc_r,
    const float* __restrict__ asc_k, int t0)
{
    const size_t PSPL = (size_t)DELAY_ * BH_;
    int idx = blockIdx.x * 256 + threadIdx.x;
    int h = idx & (H_ - 1);
    float v, f, a0, a1;
    if (t0 == 0) { v = 0.f; f = 0.f; a0 = 0.f; a1 = 0.f; }
    else { v = volt[idx]; f = fire[idx]; a0 = asc[idx]; a1 = asc[BH_ + idx]; }
    float th = thresh[h], dtk = DT_ * km[h];
    float amp0 = asc_amp[h], amp1 = asc_amp[H_ + h];
    float r0 = asc_r[h], r1 = asc_r[H_ + h];
    float d0 = expf(-DT_ * asc_k[h]), d1 = expf(-DT_ * asc_k[H_ + h]);
    unsigned short pa[NP], pb[NP];
    #pragma unroll
    for (int s = 0; s < NP; ++s) pa[s] = P[s * PSPL + idx];
    for (int t = 0; t < DELAY_; ++t) {
        if (t + 1 < DELAY_) {
            #pragma unroll
            for (int s = 0; s < NP; ++s)
                pb[s] = P[s * PSPL + (size_t)(t + 1) * BH_ + idx];
        }
        float syn = 0.f;
        #pragma unroll
        for (int s = 0; s < NP; ++s) syn += bf2f(pa[s]);
        float na0 = a0 * d0 + f * (r0 * a0 + amp0);
        float na1 = a1 * d1 + f * (r1 * a1 + amp1);
        a0 = na0; a1 = na1;
        float tot = syn + a0 + a1;
        v = v * (1.f - f);
        v = v + dtk * (RMEM_ * tot - v);
        f = 1.f / (1.f + __expf(-(v - th)));
        F[(size_t)(t0 + t) * BH_ + idx] = f2bf(f);
        #pragma unroll
        for (int s = 0; s < NP; ++s) pa[s] = pb[s];
    }
    volt[idx] = v; fire[idx] = f;
    asc[idx] = a0; asc[BH_ + idx] = a1;
}

extern "C" void kernel_launch(void* const* d_in, const int* in_sizes, int n_in,
                              void* d_out, int out_size, void* d_ws, size_t ws_size,
                              hipStream_t stream) {
    const float* x       = (const float*)d_in[0];
    const float* w_iv    = (const float*)d_in[1];
    const float* w_lat   = (const float*)d_in[2];
    const float* thresh  = (const float*)d_in[3];
    const float* km      = (const float*)d_in[4];
    const float* asc_amp = (const float*)d_in[5];
    const float* asc_r   = (const float*)d_in[6];
    const float* asc_k   = (const float*)d_in[7];
    const float* w_out   = (const float*)d_in[8];
    const float* b_out   = (const float*)d_in[9];
    float* out = (float*)d_out;

    char* ws = (char*)d_ws;
    unsigned short* P     = (unsigned short*)ws;                          // 10,485,760 (2 partials)
    unsigned short* Fb    = (unsigned short*)(ws + 10485760);             // 52,428,800 (T,B,H) bf16
    unsigned short* xbt   = (unsigned short*)(ws + 62914560);             // 13,107,200 (T*B x I) bf16
    unsigned short* WcatT = (unsigned short*)(ws + 76021760);             // 10,485,760 (H x 2560)
    unsigned short* WoutT = (unsigned short*)(ws + 86507520);             //  2,097,152 (O x H)
    float*          volt  = (float*)(ws + 88604672);
    float*          fire  = (float*)(ws + 89128960);
    float*          asc   = (float*)(ws + 89653248);                      // 2*BH f32

    // preamble: 3 transposes (4096+1024+1024 blocks) + x convert (6400 blocks)
    {
        TJob j0{w_lat, WcatT, H_, H_, 2560, 0,    H_ / 32};
        TJob j1{w_iv,  WcatT, I_, H_, 2560, 2048, H_ / 32};
        TJob j2{w_out, WoutT, H_, O_, 2048, 0,    O_ / 32};
        k_pre<<<6144 + 6400, 256, 0, stream>>>(j0, j1, j2, 4096, 1024, 1024, x, xbt);
    }

    // chunk 0: P0 = x_0 @ W_iv  (K=512 via x-part of Wcat) : <64,64> 8w, 640 blocks
    k_gemm<64, 64, 4, 2><<<(DELAY_ * B_ / 64) * (H_ / 64), 512, 0, stream>>>(
        nullptr, xbt, WcatT, P, nullptr,
        0, I_, 0, I_, 2560, 2048, H_, 0, 1, 1, 0, H_ / 64, DELAY_ * B_ / 64);
    k_rec<1><<<BH_ / 256, 256, 0, stream>>>(P, Fb, volt, fire, asc,
                                            thresh, km, asc_amp, asc_r, asc_k, 0);

    for (int c = 1; c < T_ / DELAY_; ++c) {
        // {P0,P1} = [F[c-1] | x_c] @ Wcat : <128,64> 8w, split-K=2, 640 blocks
        k_gemm<128, 64, 4, 2><<<(DELAY_ * B_ / 128) * (H_ / 64) * 2, 512, 0, stream>>>(
            Fb + (size_t)(c - 1) * DELAY_ * BH_, xbt + (size_t)c * DELAY_ * B_ * I_,
            WcatT, P, nullptr,
            H_, H_ + I_, H_, I_, 2560, 0, H_, 0, 1, 2, (long long)DELAY_ * BH_,
            H_ / 64, DELAY_ * B_ / 128);
        k_rec<2><<<BH_ / 256, 256, 0, stream>>>(P, Fb, volt, fire, asc,
                                                thresh, km, asc_amp, asc_r, asc_k, c * DELAY_);
    }

    // out = F @ w_out + b_out : <128,128> 16 waves / 1024 thr, 400 blocks
    k_gemm<128, 128, 4, 4><<<(B_ * T_ / 128) * (O_ / 128), 1024, 0, stream>>>(
        nullptr, Fb, WoutT, out, b_out,
        0, H_, 0, H_, H_, 0, O_, 1, 0, 1, 0, O_ / 128, B_ * T_ / 128);
}